// Round 6
// baseline (910.352 us; speedup 1.0000x reference)
//
#include <hip/hip_runtime.h>

namespace {
typedef float v2f __attribute__((ext_vector_type(2)));
constexpr int kB = 256;
constexpr int kS = 2048;
constexpr int kV = 10;
constexpr int kE = 32;
constexpr int kH = 64;
constexpr int kO = 10;
constexpr int kT = 16;      // steps per tile
constexpr int kPad = 68;    // LDS row stride in floats (272 B, 16B-aligned)
constexpr int kTiles = kS / kT;   // 128
// Fold tanh's 2x and log2(e) into weights: s = kC*(xw + h.Wh + b), e^{2p} = 2^s
constexpr float kC = 2.885390081777927f;   // 2*log2(e)

__device__ __forceinline__ float step_tanh(float s) {
    s = __builtin_amdgcn_fmed3f(s, -26.f, 26.f);
    float e = __builtin_amdgcn_exp2f(s);
    float r = __builtin_amdgcn_rcpf(e + 1.f);
    return fmaf(-2.f, r, 1.f);              // tanh = 1 - 2/(e^{2p}+1)
}

__device__ __forceinline__ void do_logits(const float* __restrict__ hb,
                                          const float (* __restrict__ WdT)[kPad],
                                          const float* __restrict__ bdL,
                                          float* __restrict__ out, int obase, int l)
{
    #pragma unroll
    for (int r = 0; r < 3; ++r) {
        int f = r * 64 + l;                  // flat (t_local, o), 160 total
        if (f < kT * kO) {
            int tl = f / kO;
            int o  = f - tl * kO;
            const float4* hb4 = reinterpret_cast<const float4*>(hb + tl * kPad);
            const float4* wd4 = reinterpret_cast<const float4*>(&WdT[o][0]);
            float a0 = bdL[o], a1 = 0.f, a2 = 0.f, a3 = 0.f;
            #pragma unroll
            for (int c = 0; c < kH / 4; ++c) {
                float4 h4 = hb4[c];
                float4 w4 = wd4[c];
                a0 = fmaf(h4.x, w4.x, a0);
                a1 = fmaf(h4.y, w4.y, a1);
                a2 = fmaf(h4.z, w4.z, a2);
                a3 = fmaf(h4.w, w4.w, a3);
            }
            out[obase + f] = (a0 + a1) + (a2 + a3);   // coalesced
        }
    }
}

// split-K quad c (k = kbase+4c..+3): own-output accs O0/O1, partner accs P0/P1
// (whcA2 = own column l, whcB2 = partner column l^32 — shared by both seqs)
#define ACQ(Q, c, O0, O1, P0, P1)                                           \
    do {                                                                    \
        v2f lo_; lo_.x = (Q).x; lo_.y = (Q).y;                              \
        v2f hi_; hi_.x = (Q).z; hi_.y = (Q).w;                              \
        O0 = lo_ * whcA2[2 * (c)]     + O0;                                 \
        O1 = hi_ * whcA2[2 * (c) + 1] + O1;                                 \
        P0 = lo_ * whcB2[2 * (c)]     + P0;                                 \
        P1 = hi_ * whcB2[2 * (c) + 1] + P1;                                 \
    } while (0)

// Wave 0 runs TWO sequences' recurrence chains in one instruction stream:
// chain B's loads/FMAs fill chain A's DS-latency and dependency-stall slots
// (R3/R4 lesson: one chain leaves ~200cy/step of unfilled slots).
// Split-K: each lane reads its 32-wide k-half (8x ds_read_b128 per seq),
// computes own-output + partner(l^32) partials; the partner half is combined
// via __shfl(p, l^32, 64) — the R0-proven exchange (the R5 permlane asm
// produced wrong results; reverted to the known-good primitive).
// Wave 1: logits for the previous tile of both sequences.
__global__ __launch_bounds__(128, 1)
void rnn_fused(const int* __restrict__ num1, const int* __restrict__ num2,
               const float* __restrict__ embed, const float* __restrict__ Wx,
               const float* __restrict__ Wh, const float* __restrict__ bias,
               const float* __restrict__ Wd, const float* __restrict__ bd,
               float* __restrict__ out)
{
    const int rowA = blockIdx.x * 2;       // two sequences per block
    const int rowB = rowA + 1;
    const int tid = threadIdx.x;
    const int w   = tid >> 6;     // 0 = dual recurrence wave, 1 = logits wave
    const int l   = tid & 63;     // lane owns hidden unit l
    const int lx  = l ^ 32;       // split-K partner lane
    const int kbase = (l >> 5) * 32;       // this lane's k-half

    __shared__ __align__(16) float TT[kV * kV][kH];      // kC*(xw+b), 100 rows
    __shared__ __align__(16) float hbufA[2][kT][kPad];   // seq A h history
    __shared__ __align__(16) float hbufB[2][kT][kPad];   // seq B h history
    __shared__ __align__(16) float WdT[kO][kPad];
    __shared__ float bdL[kO];

    v2f whcA2[kH / 4], whcB2[kH / 4];   // kC*Wh k-half cols: own l / partner l^32
    int idxA_next = 0, idxB_next = 0;
    const int lane16 = l & 15;
    const int nbA = rowA * kS, nbB = rowB * kS;
    const int orowA = rowA * (kS * kO), orowB = rowB * (kS * kO);

    if (w == 0) {
        // ---- one-time setup: input-projection table + Wh half-columns ----
        float wxc[2 * kE];
        #pragma unroll
        for (int k = 0; k < 2 * kE; ++k) wxc[k] = Wx[k * kH + l];  // Wx column l
        float bj = bias[l];
        float t1[kV], t2[kV];
        #pragma unroll
        for (int v = 0; v < kV; ++v) {
            float a0 = 0.f, a1 = 0.f;
            #pragma unroll
            for (int k = 0; k < kE; ++k) {
                float e = embed[v * kE + k];   // lane-uniform -> s_load
                a0 = fmaf(e, wxc[k], a0);
                a1 = fmaf(e, wxc[kE + k], a1);
            }
            t1[v] = a0; t2[v] = a1;
        }
        #pragma unroll
        for (int v1 = 0; v1 < kV; ++v1)
            #pragma unroll
            for (int v2 = 0; v2 < kV; ++v2)
                TT[v1 * kV + v2][l] = kC * (t1[v1] + t2[v2] + bj);
        #pragma unroll
        for (int i = 0; i < kH / 4; ++i) {      // 16 pairs per table
            v2f ta, tb;
            ta.x = kC * Wh[(kbase + 2 * i)     * kH + l];
            ta.y = kC * Wh[(kbase + 2 * i + 1) * kH + l];
            tb.x = kC * Wh[(kbase + 2 * i)     * kH + lx];
            tb.y = kC * Wh[(kbase + 2 * i + 1) * kH + lx];
            whcA2[i] = ta; whcB2[i] = tb;
        }
        hbufA[1][kT - 1][l] = 0.f;   // h_{-1}=0 for both chains
        hbufB[1][kT - 1][l] = 0.f;
        idxA_next = num1[nbA + lane16] * kV + num2[nbA + lane16];
        idxB_next = num1[nbB + lane16] * kV + num2[nbB + lane16];
        __builtin_amdgcn_s_setprio(1);   // favor the chain wave in arbitration
    } else {
        #pragma unroll
        for (int o = 0; o < kO; ++o) WdT[o][l] = Wd[l * kO + o];
        if (l < kO) bdL[l] = bd[l];
    }
    __syncthreads();

    const float* prevA = &hbufA[1][kT - 1][0];   // rolling h_{t-1} rows
    const float* prevB = &hbufB[1][kT - 1][0];

    for (int ti = 0; ti < kTiles; ++ti) {
        if (w == 0) {
            const int idxvA = idxA_next, idxvB = idxB_next;
            if (ti + 1 < kTiles) {
                int ta = nbA + (ti + 1) * kT + lane16;
                int tb = nbB + (ti + 1) * kT + lane16;
                idxA_next = num1[ta] * kV + num2[ta];   // prefetch next tile idx
                idxB_next = num1[tb] * kV + num2[tb];
            }
            float* curA = &hbufA[ti & 1][0][0];
            float* curB = &hbufB[ti & 1][0][0];
            #pragma unroll 1
            for (int tl = 0; tl < kT; ++tl) {
                const int sA = __builtin_amdgcn_readlane(idxvA, tl);
                const int sB = __builtin_amdgcn_readlane(idxvB, tl);
                const float xwA = TT[sA][l];    // issued early, consumed late
                const float xwB = TT[sB][l];
                const float4* hqA = reinterpret_cast<const float4*>(prevA + kbase);
                const float4* hqB = reinterpret_cast<const float4*>(prevB + kbase);
                float4 A0 = hqA[0], A1 = hqA[1], A2 = hqA[2], A3 = hqA[3];
                float4 A4 = hqA[4], A5 = hqA[5], A6 = hqA[6], A7 = hqA[7];
                float4 B0 = hqB[0], B1 = hqB[1], B2 = hqB[2], B3 = hqB[3];
                float4 B4 = hqB[4], B5 = hqB[5], B6 = hqB[6], B7 = hqB[7];
                __builtin_amdgcn_sched_barrier(0);     // batch loads at step head
                v2f Ao0; Ao0.x = xwA; Ao0.y = 0.f;     // xw folded into acc init
                v2f Ao1 = {0.f, 0.f}, Ap0 = {0.f, 0.f}, Ap1 = {0.f, 0.f};
                v2f Bo0; Bo0.x = xwB; Bo0.y = 0.f;
                v2f Bo1 = {0.f, 0.f}, Bp0 = {0.f, 0.f}, Bp1 = {0.f, 0.f};
                // chain A MACs (data returns first), then chain B
                ACQ(A0, 0, Ao0, Ao1, Ap0, Ap1); ACQ(A1, 1, Ao0, Ao1, Ap0, Ap1);
                ACQ(A2, 2, Ao0, Ao1, Ap0, Ap1); ACQ(A3, 3, Ao0, Ao1, Ap0, Ap1);
                ACQ(A4, 4, Ao0, Ao1, Ap0, Ap1); ACQ(A5, 5, Ao0, Ao1, Ap0, Ap1);
                ACQ(A6, 6, Ao0, Ao1, Ap0, Ap1); ACQ(A7, 7, Ao0, Ao1, Ap0, Ap1);
                ACQ(B0, 0, Bo0, Bo1, Bp0, Bp1); ACQ(B1, 1, Bo0, Bo1, Bp0, Bp1);
                ACQ(B2, 2, Bo0, Bo1, Bp0, Bp1); ACQ(B3, 3, Bo0, Bo1, Bp0, Bp1);
                ACQ(B4, 4, Bo0, Bo1, Bp0, Bp1); ACQ(B5, 5, Bo0, Bo1, Bp0, Bp1);
                ACQ(B6, 6, Bo0, Bo1, Bp0, Bp1); ACQ(B7, 7, Bo0, Bo1, Bp0, Bp1);
                // partner partials first; both shfls issue together so their
                // DS latencies overlap; own reductions fill the wait window
                v2f Apv = Ap0 + Ap1;  float pParA = Apv.x + Apv.y;
                v2f Bpv = Bp0 + Bp1;  float pParB = Bpv.x + Bpv.y;
                float othA = __shfl(pParA, lx, 64);    // R0-proven exchange
                float othB = __shfl(pParB, lx, 64);
                v2f Aov = Ao0 + Ao1;  float pOwnA = Aov.x + Aov.y;  // incl. xwA
                v2f Bov = Bo0 + Bo1;  float pOwnB = Bov.x + Bov.y;  // incl. xwB
                float hA = step_tanh(pOwnA + othA);
                float* wrA = curA + tl * kPad;
                wrA[l] = hA;  prevA = wrA;
                float hB = step_tanh(pOwnB + othB);
                float* wrB = curB + tl * kPad;
                wrB[l] = hB;  prevB = wrB;
            }
        } else if (ti > 0) {
            do_logits(&hbufA[(ti - 1) & 1][0][0], WdT, bdL, out,
                      orowA + (ti - 1) * kT * kO, l);
            do_logits(&hbufB[(ti - 1) & 1][0][0], WdT, bdL, out,
                      orowB + (ti - 1) * kT * kO, l);
        }
        __syncthreads();   // publish tile ti history / retire tile ti-1 reads
    }
    if (w == 1) {
        do_logits(&hbufA[(kTiles - 1) & 1][0][0], WdT, bdL, out,
                  orowA + (kS - kT) * kO, l);
        do_logits(&hbufB[(kTiles - 1) & 1][0][0], WdT, bdL, out,
                  orowB + (kS - kT) * kO, l);
    }
}
#undef ACQ
} // namespace

extern "C" void kernel_launch(void* const* d_in, const int* in_sizes, int n_in,
                              void* d_out, int out_size, void* d_ws, size_t ws_size,
                              hipStream_t stream) {
    (void)in_sizes; (void)n_in; (void)d_ws; (void)ws_size; (void)out_size;
    rnn_fused<<<dim3(kB / 2), dim3(128), 0, stream>>>(
        (const int*)d_in[0], (const int*)d_in[1],
        (const float*)d_in[2], (const float*)d_in[3],
        (const float*)d_in[4], (const float*)d_in[5],
        (const float*)d_in[6], (const float*)d_in[7],
        (float*)d_out);
}

// Round 8
// 456.186 us; speedup vs baseline: 1.9956x; 1.9956x over previous
//
#include <hip/hip_runtime.h>

namespace {
typedef float v2f __attribute__((ext_vector_type(2)));
typedef unsigned u32x2 __attribute__((ext_vector_type(2)));
constexpr int kB = 256;
constexpr int kS = 2048;
constexpr int kV = 10;
constexpr int kE = 32;
constexpr int kH = 64;
constexpr int kO = 10;
constexpr int kT = 16;      // steps per tile
constexpr int kPad = 68;    // LDS row stride in floats (272 B, 16B-aligned)
constexpr int kTiles = kS / kT;   // 128
// Fold tanh's 2x and log2(e) into weights: s = kC*(xw + h.Wh + b), e^{2p} = 2^s
constexpr float kC = 2.885390081777927f;   // 2*log2(e)

__device__ __forceinline__ float step_tanh(float s) {
    s = __builtin_amdgcn_fmed3f(s, -26.f, 26.f);
    float e = __builtin_amdgcn_exp2f(s);
    float r = __builtin_amdgcn_rcpf(e + 1.f);
    return fmaf(-2.f, r, 1.f);              // tanh = 1 - 2/(e^{2p}+1)
}

// Partner-half exchange lanes l <-> l^32 on the VALU pipe (no DS round trip),
// via the documented gfx950 builtin (T12/m255). It returns BOTH post-swap
// registers {vdst', src'}; passing p twice, one of them keeps p and the other
// holds p[l^32] (which one depends on the half-swap convention), so
// (vdst' + src') - p == p[l^32] under either convention. The two hand-rolled
// asm attempts (R5/R7) produced garbage — builtin removes coalescing/modifier
// failure modes entirely.
__device__ __forceinline__ float swap32(float p) {
    u32x2 r = __builtin_amdgcn_permlane32_swap(__float_as_uint(p),
                                               __float_as_uint(p),
                                               false, false);
    return (__uint_as_float(r.x) + __uint_as_float(r.y)) - p;
}

__device__ __forceinline__ void do_logits(const float* __restrict__ hb,
                                          const float (* __restrict__ WdT)[kPad],
                                          const float* __restrict__ bdL,
                                          float* __restrict__ out, int obase, int l)
{
    #pragma unroll
    for (int r = 0; r < 3; ++r) {
        int f = r * 64 + l;                  // flat (t_local, o), 160 total
        if (f < kT * kO) {
            int tl = f / kO;
            int o  = f - tl * kO;
            const float4* hb4 = reinterpret_cast<const float4*>(hb + tl * kPad);
            const float4* wd4 = reinterpret_cast<const float4*>(&WdT[o][0]);
            float a0 = bdL[o], a1 = 0.f, a2 = 0.f, a3 = 0.f;
            #pragma unroll
            for (int c = 0; c < kH / 4; ++c) {
                float4 h4 = hb4[c];
                float4 w4 = wd4[c];
                a0 = fmaf(h4.x, w4.x, a0);
                a1 = fmaf(h4.y, w4.y, a1);
                a2 = fmaf(h4.z, w4.z, a2);
                a3 = fmaf(h4.w, w4.w, a3);
            }
            out[obase + f] = (a0 + a1) + (a2 + a3);   // coalesced
        }
    }
}

// Wave 0: serial recurrence, split-K: each lane reads only its 32-wide k-half
// (8x ds_read_b128, uniform-address broadcast) and accumulates that half for
// its own output l (incl. xw) and for partner output l^32; halves are merged
// with the VALU-pipe permlane swap (cost model R1/R2/R4/R6: step ~= 12cy*DS +
// 3cy*VALU + 150cy fixed -> halving the 16 b128 reads is the big lever, and
// the combine must NOT be a DS op like __shfl).
// Wave 1: logits for the previous tile from the double-buffered h history.
__global__ __launch_bounds__(128, 1)
void rnn_fused(const int* __restrict__ num1, const int* __restrict__ num2,
               const float* __restrict__ embed, const float* __restrict__ Wx,
               const float* __restrict__ Wh, const float* __restrict__ bias,
               const float* __restrict__ Wd, const float* __restrict__ bd,
               float* __restrict__ out)
{
    const int row = blockIdx.x;   // one sequence per block
    const int tid = threadIdx.x;
    const int w   = tid >> 6;     // 0 = recurrence wave, 1 = logits wave
    const int l   = tid & 63;     // lane owns hidden unit l
    const int lx  = l ^ 32;       // split-K partner lane
    const int kbase = (l >> 5) * 32;       // this lane's k-half

    __shared__ __align__(16) float TT[kV * kV][kH];     // kC*(xw+b), 100 rows
    __shared__ __align__(16) float hbuf[2][kT][kPad];   // double-buffered h history
    __shared__ __align__(16) float WdT[kO][kPad];
    __shared__ float bdL[kO];

    v2f whcA2[kH / 4], whcB2[kH / 4];   // kC*Wh k-half cols: own l / partner l^32
    int idx_next = 0;
    const int lane16 = l & 15;
    const int nb = row * kS;
    const int orow = row * (kS * kO);

    if (w == 0) {
        // ---- one-time setup: input-projection table + Wh half-columns ----
        float wxc[2 * kE];
        #pragma unroll
        for (int k = 0; k < 2 * kE; ++k) wxc[k] = Wx[k * kH + l];  // Wx column l
        float bj = bias[l];
        float t1[kV], t2[kV];
        #pragma unroll
        for (int v = 0; v < kV; ++v) {
            float a0 = 0.f, a1 = 0.f;
            #pragma unroll
            for (int k = 0; k < kE; ++k) {
                float e = embed[v * kE + k];   // lane-uniform -> s_load
                a0 = fmaf(e, wxc[k], a0);
                a1 = fmaf(e, wxc[kE + k], a1);
            }
            t1[v] = a0; t2[v] = a1;
        }
        #pragma unroll
        for (int v1 = 0; v1 < kV; ++v1)
            #pragma unroll
            for (int v2 = 0; v2 < kV; ++v2)
                TT[v1 * kV + v2][l] = kC * (t1[v1] + t2[v2] + bj);
        #pragma unroll
        for (int i = 0; i < kH / 4; ++i) {      // 16 packed pairs per table
            v2f ta, tb;
            ta.x = kC * Wh[(kbase + 2 * i)     * kH + l];
            ta.y = kC * Wh[(kbase + 2 * i + 1) * kH + l];
            tb.x = kC * Wh[(kbase + 2 * i)     * kH + lx];
            tb.y = kC * Wh[(kbase + 2 * i + 1) * kH + lx];
            whcA2[i] = ta; whcB2[i] = tb;
        }
        hbuf[1][kT - 1][l] = 0.f;   // h_{-1}=0: tile 0 broadcast reads this row
        idx_next = num1[nb + lane16] * kV + num2[nb + lane16];   // tile 0 idx
        __builtin_amdgcn_s_setprio(1);   // favor the chain wave in arbitration
    } else {
        #pragma unroll
        for (int o = 0; o < kO; ++o) WdT[o][l] = Wd[l * kO + o];
        if (l < kO) bdL[l] = bd[l];
    }
    __syncthreads();

    const float* prevRow = &hbuf[1][kT - 1][0];   // rolling h_{t-1} row

    for (int ti = 0; ti < kTiles; ++ti) {
        if (w == 0) {
            const int idxv = idx_next;
            if (ti + 1 < kTiles) {
                int tt = nb + (ti + 1) * kT + lane16;
                idx_next = num1[tt] * kV + num2[tt];   // prefetch next tile idx
            }
            float* curBase = &hbuf[ti & 1][0][0];
            #pragma unroll 1
            for (int tl = 0; tl < kT; ++tl) {
                const int sidx = __builtin_amdgcn_readlane(idxv, tl); // dyn lane
                const float xwv = TT[sidx][l];   // issued early, consumed late
                const float4* hq = reinterpret_cast<const float4*>(prevRow + kbase);
                float4 q[8];
                #pragma unroll
                for (int c = 0; c < 8; ++c) q[c] = hq[c];   // k-half bcast
                __builtin_amdgcn_sched_barrier(0);          // loads at step head
                v2f o0; o0.x = xwv; o0.y = 0.f;  // xw folded into own-acc init
                v2f o1 = {0.f, 0.f}, r0 = {0.f, 0.f}, r1 = {0.f, 0.f};
                #pragma unroll
                for (int c = 0; c < 8; ++c) {
                    v2f lo; lo.x = q[c].x; lo.y = q[c].y;
                    v2f hi; hi.x = q[c].z; hi.y = q[c].w;
                    o0 = lo * whcA2[2 * c]     + o0;   // own output, own k-half
                    o1 = hi * whcA2[2 * c + 1] + o1;
                    r0 = lo * whcB2[2 * c]     + r0;   // partner output partial
                    r1 = hi * whcB2[2 * c + 1] + r1;
                }
                v2f rv = r0 + r1;  float pPar = rv.x + rv.y;
                float oth = swap32(pPar);          // VALU-pipe half exchange
                v2f ov = o0 + o1;  float pOwn = ov.x + ov.y;   // incl. xw
                float hcur = step_tanh(pOwn + oth);
                float* wr = curBase + tl * kPad;
                wr[l] = hcur;              // history row (logits + next bcast)
                prevRow = wr;
            }
        } else if (ti > 0) {
            do_logits(&hbuf[(ti - 1) & 1][0][0], WdT, bdL, out,
                      orow + (ti - 1) * kT * kO, l);
        }
        __syncthreads();   // publish tile ti history / retire tile ti-1 reads
    }
    if (w == 1)
        do_logits(&hbuf[(kTiles - 1) & 1][0][0], WdT, bdL, out,
                  orow + (kS - kT) * kO, l);
}
} // namespace

extern "C" void kernel_launch(void* const* d_in, const int* in_sizes, int n_in,
                              void* d_out, int out_size, void* d_ws, size_t ws_size,
                              hipStream_t stream) {
    (void)in_sizes; (void)n_in; (void)d_ws; (void)ws_size; (void)out_size;
    rnn_fused<<<dim3(kB), dim3(128), 0, stream>>>(
        (const int*)d_in[0], (const int*)d_in[1],
        (const float*)d_in[2], (const float*)d_in[3],
        (const float*)d_in[4], (const float*)d_in[5],
        (const float*)d_in[6], (const float*)d_in[7],
        (float*)d_out);
}